// Round 4
// baseline (288.968 us; speedup 1.0000x reference)
//
#include <hip/hip_runtime.h>

typedef __attribute__((ext_vector_type(8))) short short8;
typedef __attribute__((ext_vector_type(4))) float f32x4;

#define DEVI static __device__ __forceinline__

constexpr int NB   = 4;     // batch
constexpr int NH   = 2;     // heads
constexpr int SEQ  = 2048;  // Lq = Lk
constexpr int DM   = 512;   // d_model
constexpr int DKV  = 64;    // d_k = d_v
constexpr int HDIM = 128;   // NH * DKV

DEVI unsigned short f2bf(float f) {
    union { float f; unsigned u; } v; v.f = f;
    unsigned r = v.u + 0x7FFFu + ((v.u >> 16) & 1u);
    return (unsigned short)(r >> 16);
}
DEVI float bf2f(unsigned short s) {
    union { unsigned u; float f; } v; v.u = ((unsigned)s) << 16; return v.f;
}
// async global->LDS, 16B per lane. LDS dest = wave-uniform base + lane*16.
DEVI void async16(const void* g, void* l) {
    __builtin_amdgcn_global_load_lds(
        (const __attribute__((address_space(1))) unsigned int*)g,
        (__attribute__((address_space(3))) unsigned int*)l, 16, 0, 0);
}

// ---------------------------------------------------------------------------
// k_prep: weights f32 -> bf16, transposed so MFMA B-operand rows are K-contig.
__global__ __launch_bounds__(256) void k_prep(
    const float* __restrict__ Wq, const float* __restrict__ Wk,
    const float* __restrict__ Wv, const float* __restrict__ Wo,
    unsigned short* __restrict__ Wqt, unsigned short* __restrict__ Wkt,
    unsigned short* __restrict__ Wvt, unsigned short* __restrict__ Wot) {
    int id = blockIdx.x * 256 + threadIdx.x;        // 0 .. 262143
    int which = id >> 16;
    int rem = id & 65535;
    if (which < 3) {
        const float* W = which == 0 ? Wq : (which == 1 ? Wk : Wv);
        unsigned short* Wt = which == 0 ? Wqt : (which == 1 ? Wkt : Wvt);
        int n = rem >> 9, k = rem & 511;            // dst [128][512]
        Wt[rem] = f2bf(W[k * HDIM + n]);
    } else {
        int n = rem >> 7, k = rem & 127;            // dst [512][128]
        Wot[rem] = f2bf(Wo[k * DM + n]);
    }
}

// ---------------------------------------------------------------------------
// k_proj: X[8192,512] @ W[512,128] + b  ->  per-head bf16 layouts.
// Also accumulates colsumv[ksp][b][h*64+d] = sum_k v (per k-quarter) for the
// out = S@V - L*colsumV decomposition used by k_pass2.
__global__ __launch_bounds__(256) void k_proj(
    const float* __restrict__ Qg, const float* __restrict__ Kg, const float* __restrict__ Vg,
    const unsigned short* __restrict__ Wqt, const unsigned short* __restrict__ Wkt,
    const unsigned short* __restrict__ Wvt,
    const float* __restrict__ bq, const float* __restrict__ bk, const float* __restrict__ bv,
    unsigned short* __restrict__ qs, unsigned short* __restrict__ kb,
    unsigned short* __restrict__ vt, float* __restrict__ colsumv) {
    __shared__ unsigned short lA[64 * 72];    // A tile, +8 pad (bank shift 4)
    __shared__ unsigned short lB[128 * 64];   // B tile, xor-swizzled chunks

    const int y = blockIdx.y;
    const float* X = y == 0 ? Qg : (y == 1 ? Kg : Vg);
    const unsigned short* Wt = y == 0 ? Wqt : (y == 1 ? Wkt : Wvt);
    const float* bias = y == 0 ? bq : (y == 1 ? bk : bv);
    const float scal = y == 0 ? 0.125f : 1.0f;   // fold 1/sqrt(dk) into q
    const int row0 = blockIdx.x * 64;
    const int tid = threadIdx.x, lane = tid & 63, wv = tid >> 6;
    const int l16 = lane & 15, lq4 = lane >> 4;
    const int wr = wv >> 1, wc = wv & 1;

    f32x4 acc[2][4];
    #pragma unroll
    for (int i = 0; i < 2; ++i)
        #pragma unroll
        for (int j = 0; j < 4; ++j) acc[i][j] = f32x4{0.f, 0.f, 0.f, 0.f};

    const int arow = tid >> 2, ac0 = (tid & 3) * 16;

    for (int kc = 0; kc < 8; ++kc) {
        {
            const float* src = X + (size_t)(row0 + arow) * DM + kc * 64 + ac0;
            unsigned short* dst = &lA[arow * 72 + ac0];
            #pragma unroll
            for (int i = 0; i < 4; ++i) {
                f32x4 v = __builtin_nontemporal_load((const f32x4*)(src + 4 * i));
                unsigned p0 = (unsigned)f2bf(v.x) | ((unsigned)f2bf(v.y) << 16);
                unsigned p1 = (unsigned)f2bf(v.z) | ((unsigned)f2bf(v.w) << 16);
                *(unsigned*)(dst + 4 * i) = p0;
                *(unsigned*)(dst + 4 * i + 2) = p1;
            }
        }
        // stage B swizzled: chunk c' in LDS holds global chunk c = c'^(row&7)
        #pragma unroll
        for (int c = 0; c < 4; ++c) {
            int chunk = wv * 4 + c;
            int flat = chunk * 64 + lane;
            int row = flat >> 3, cp = flat & 7, cc = cp ^ (row & 7);
            const void* g = (const char*)Wt + (size_t)row * 1024 + kc * 128 + cc * 16;
            void* l = (char*)lB + chunk * 1024 + lane * 16;
            async16(g, l);
        }
        __syncthreads();

        #pragma unroll
        for (int ks = 0; ks < 2; ++ks) {
            short8 a[2], b[4];
            #pragma unroll
            for (int mt = 0; mt < 2; ++mt) {
                int m = wr * 32 + mt * 16 + l16;
                a[mt] = *(const short8*)&lA[m * 72 + ks * 32 + lq4 * 8];
            }
            #pragma unroll
            for (int nt = 0; nt < 4; ++nt) {
                int n = wc * 64 + nt * 16 + l16;
                b[nt] = *(const short8*)&lB[n * 64 + (((ks * 4 + lq4) ^ (n & 7)) * 8)];
            }
            #pragma unroll
            for (int mt = 0; mt < 2; ++mt)
                #pragma unroll
                for (int nt = 0; nt < 4; ++nt)
                    acc[mt][nt] = __builtin_amdgcn_mfma_f32_16x16x32_bf16(
                        a[mt], b[nt], acc[mt][nt], 0, 0, 0);
        }
        __syncthreads();
    }

    if (y < 2) {
        unsigned short* dstp = (y == 0) ? qs : kb;
        #pragma unroll
        for (int mt = 0; mt < 2; ++mt)
            #pragma unroll
            for (int nt = 0; nt < 4; ++nt) {
                int col = wc * 64 + nt * 16 + l16;
                float bb = bias[col];
                int h = col >> 6, d = col & 63;
                #pragma unroll
                for (int r = 0; r < 4; ++r) {
                    int row = row0 + wr * 32 + mt * 16 + lq4 * 4 + r;
                    int b = row >> 11, pos = row & 2047;
                    float val = (acc[mt][nt][r] + bb) * scal;
                    dstp[((size_t)(b * NH + h) * SEQ + pos) * DKV + d] = f2bf(val);
                }
            }
    } else {
        // V: bounce through LDS -> vt[b][h][d][kpos]; then colsum atomics.
        #pragma unroll
        for (int mt = 0; mt < 2; ++mt)
            #pragma unroll
            for (int nt = 0; nt < 4; ++nt) {
                int col = wc * 64 + nt * 16 + l16;
                float bb = bias[col];
                #pragma unroll
                for (int r = 0; r < 4; ++r) {
                    int mrow = wr * 32 + mt * 16 + lq4 * 4 + r;
                    lB[col * 64 + mrow] = f2bf(acc[mt][nt][r] + bb);
                }
            }
        __syncthreads();
        {
            int c = tid >> 1, mp = (tid & 1) * 32;
            int b = row0 >> 11, kpos0 = row0 & 2047;
            int h = c >> 6, d = c & 63;
            unsigned short* dst = vt + ((size_t)(b * NH + h) * DKV + d) * SEQ + kpos0 + mp;
            const unsigned short* srcl = &lB[c * 64 + mp];
            #pragma unroll
            for (int i = 0; i < 4; ++i)
                *(uint4*)(dst + 8 * i) = *(const uint4*)(srcl + 8 * i);
        }
        // colsum over this block's 64 k-positions (all within one quarter)
        {
            int col = tid >> 1, half = tid & 1;
            const unsigned short* p = &lB[col * 64 + half * 32];
            float s = 0.f;
            #pragma unroll
            for (int i = 0; i < 4; ++i) {
                short8 hv = *(const short8*)(p + 8 * i);
                #pragma unroll
                for (int j = 0; j < 8; ++j) s += bf2f((unsigned short)hv[j]);
            }
            s += __shfl_xor(s, 1);
            if (half == 0) {
                int ksp2 = (row0 & 2047) >> 9, bb = row0 >> 11;
                atomicAdd(&colsumv[((size_t)ksp2 * NB + bb) * HDIM + col], s);
            }
        }
    }
}

// ---------------------------------------------------------------------------
// k_pass1: per (b,h,64-q-tile,k-quarter): compute s = masked 10*tanh(qk/8),
// store s (bf16) to sws[bh][q][k]; accumulate partial sum_k exp(s) -> Lpart.
// grid 1024 = 8 bh * 32 q-tiles * 4 k-quarters.
__global__ __launch_bounds__(256) void k_pass1(
    const unsigned short* __restrict__ qs, const unsigned short* __restrict__ kb,
    const int* __restrict__ maskg, unsigned short* __restrict__ sws,
    float* __restrict__ Lpart) {
    __shared__ unsigned short lK[128 * 64];   // xor-swizzled chunks
    __shared__ unsigned short lS[64 * 136];   // s tile [q][kpos], +8 pad
    __shared__ int lM[128];
    __shared__ float lsumW[4 * 64];

    const int bx = blockIdx.x;
    const int ksp = bx & 3;
    const int qt = (bx >> 2) & 31;
    const int bh = bx >> 7;
    const int qbase = qt * 64;
    const int b = bh >> 1;
    const int tid = threadIdx.x, lane = tid & 63, wv = tid >> 6;
    const int l16 = lane & 15, lq4 = lane >> 4;

    short8 aq[4][2];
    #pragma unroll
    for (int mt = 0; mt < 4; ++mt)
        #pragma unroll
        for (int ks = 0; ks < 2; ++ks) {
            size_t off = ((size_t)bh * SEQ + qbase + mt * 16 + l16) * DKV + ks * 32 + lq4 * 8;
            aq[mt][ks] = *(const short8*)(qs + off);
        }

    float sums[4][4];
    #pragma unroll
    for (int mt = 0; mt < 4; ++mt)
        #pragma unroll
        for (int r = 0; r < 4; ++r) sums[mt][r] = 0.f;

    const char* kbase_ptr = (const char*)(kb + (size_t)bh * SEQ * DKV);

    for (int kt = ksp * 4; kt < ksp * 4 + 4; ++kt) {
        int kbase = kt * 128;
        #pragma unroll
        for (int c = 0; c < 4; ++c) {
            int chunk = wv * 4 + c;
            int flat = chunk * 64 + lane;
            int row = flat >> 3, cp = flat & 7, cc = cp ^ (row & 7);
            const void* g = kbase_ptr + (size_t)(kbase + row) * 128 + cc * 16;
            void* l = (char*)lK + chunk * 1024 + lane * 16;
            async16(g, l);
        }
        if (tid < 128) lM[tid] = maskg[b * SEQ + kbase + tid];
        __syncthreads();

        f32x4 acc[4][2];
        #pragma unroll
        for (int mt = 0; mt < 4; ++mt)
            #pragma unroll
            for (int nt = 0; nt < 2; ++nt) acc[mt][nt] = f32x4{0.f, 0.f, 0.f, 0.f};
        #pragma unroll
        for (int ks = 0; ks < 2; ++ks) {
            short8 bfr[2];
            #pragma unroll
            for (int nt = 0; nt < 2; ++nt) {
                int n = wv * 32 + nt * 16 + l16;
                bfr[nt] = *(const short8*)&lK[n * 64 + (((ks * 4 + lq4) ^ (n & 7)) * 8)];
            }
            #pragma unroll
            for (int mt = 0; mt < 4; ++mt)
                #pragma unroll
                for (int nt = 0; nt < 2; ++nt)
                    acc[mt][nt] = __builtin_amdgcn_mfma_f32_16x16x32_bf16(
                        aq[mt][ks], bfr[nt], acc[mt][nt], 0, 0, 0);
        }
        // s = masked 10*tanh(x); store bf16(trunc) to lS; sums += exp(s)
        // exp(s) = e^10 * exp(-20*r), r = 1/(1+e^{2x}); masked -> r = 1.
        #pragma unroll
        for (int nt = 0; nt < 2; ++nt) {
            int col = wv * 32 + nt * 16 + l16;
            int mv = lM[col];
            #pragma unroll
            for (int mt = 0; mt < 4; ++mt)
                #pragma unroll
                for (int r = 0; r < 4; ++r) {
                    float x = acc[mt][nt][r];
                    float e2 = __expf(2.f * x);
                    float rr = __builtin_amdgcn_rcpf(1.f + e2);
                    rr = mv ? 1.f : rr;
                    float s10 = __builtin_fmaf(-20.f, rr, 10.f);
                    union { float f; unsigned u; } cv; cv.f = s10;
                    lS[(mt * 16 + lq4 * 4 + r) * 136 + col] = (unsigned short)(cv.u >> 16);
                    float t = __expf(-20.f * rr);
                    sums[mt][r] = __builtin_fmaf(22026.465795f, t, sums[mt][r]);
                }
        }
        __syncthreads();
        // coalesced s-tile store: per instr 4 full 256B rows
        #pragma unroll
        for (int j = 0; j < 4; ++j) {
            int row = j * 16 + (tid >> 4);
            int coff = (tid & 15) * 8;
            uint4 dv = *(const uint4*)&lS[row * 136 + coff];
            *(uint4*)(sws + ((size_t)bh * SEQ + qbase + row) * SEQ + kbase + coff) = dv;
        }
    }

    #pragma unroll
    for (int mt = 0; mt < 4; ++mt)
        #pragma unroll
        for (int r = 0; r < 4; ++r) {
            float v = sums[mt][r];
            v += __shfl_xor(v, 1); v += __shfl_xor(v, 2);
            v += __shfl_xor(v, 4); v += __shfl_xor(v, 8);
            if (l16 == 0) lsumW[wv * 64 + mt * 16 + lq4 * 4 + r] = v;
        }
    __syncthreads();
    if (tid < 64) {
        float v = lsumW[tid] + lsumW[64 + tid] + lsumW[128 + tid] + lsumW[192 + tid];
        Lpart[(size_t)ksp * (8 * SEQ) + (size_t)bh * SEQ + qbase + tid] = v;
    }
}

// ---------------------------------------------------------------------------
// k_pass2: per (b,h,64-q-tile,k-quarter):
//   attn = s - L -> global f32 (nontemporal); out_part = S@V (raw s), corrected
//   by -L*colsumv in the epilogue. A-fragments of S read directly from global.
// grid 1024 = 8 bh * 32 q-tiles * 4 k-quarters.
__global__ __launch_bounds__(256) void k_pass2(
    const unsigned short* __restrict__ sws, const unsigned short* __restrict__ vt,
    const float* __restrict__ Lpart, const float* __restrict__ colsumv,
    float* __restrict__ attnG, float* __restrict__ outh2) {
    __shared__ unsigned short lV[64 * 128];   // v^T tile [d][kpos], swizzled
    __shared__ float lL[64];

    const int bx = blockIdx.x;
    const int ksp = bx & 3;
    const int qt = (bx >> 2) & 31;
    const int bh = bx >> 7;
    const int qbase = qt * 64;
    const int b = bh >> 1, h = bh & 1;
    const int tid = threadIdx.x, lane = tid & 63, wv = tid >> 6;
    const int l16 = lane & 15, lq4 = lane >> 4;

    if (tid < 64) {
        size_t idx = (size_t)bh * SEQ + qbase + tid;
        float s = Lpart[idx] + Lpart[8 * SEQ + idx] +
                  Lpart[2 * 8 * SEQ + idx] + Lpart[3 * 8 * SEQ + idx];
        lL[tid] = __logf(s);
    }
    __syncthreads();

    float Lr[4][4];
    #pragma unroll
    for (int mt = 0; mt < 4; ++mt)
        #pragma unroll
        for (int r = 0; r < 4; ++r) Lr[mt][r] = lL[mt * 16 + lq4 * 4 + r];

    f32x4 o[4];
    #pragma unroll
    for (int mt = 0; mt < 4; ++mt) o[mt] = f32x4{0.f, 0.f, 0.f, 0.f};

    const unsigned short* swsb = sws + (size_t)bh * SEQ * SEQ;

    for (int kti = 0; kti < 4; ++kti) {
        int kbase = ksp * 512 + kti * 128;
        #pragma unroll
        for (int c = 0; c < 4; ++c) {
            int chunk = wv * 4 + c;
            int flat = chunk * 64 + lane;
            int row = flat >> 4, cp = flat & 15, cc = cp ^ (row & 15);
            const void* g = (const char*)vt +
                (((size_t)bh * DKV + row) * SEQ + kbase) * 2 + cc * 16;
            void* l = (char*)lV + chunk * 1024 + lane * 16;
            async16(g, l);
        }
        __syncthreads();

        // out += S@V; A-fragments straight from global (L2/L3-hot)
        #pragma unroll
        for (int ks = 0; ks < 4; ++ks) {
            int d = wv * 16 + l16;
            short8 bfr = *(const short8*)&lV[d * 128 + (((ks * 4 + lq4) ^ (d & 15)) * 8)];
            #pragma unroll
            for (int mt = 0; mt < 4; ++mt) {
                const unsigned short* ap = swsb +
                    (size_t)(qbase + mt * 16 + l16) * SEQ + kbase + ks * 32 + lq4 * 8;
                short8 af = *(const short8*)ap;
                o[mt] = __builtin_amdgcn_mfma_f32_16x16x32_bf16(af, bfr, o[mt], 0, 0, 0);
            }
        }

        // attn = s - L -> f32 nontemporal; half-wave per 512B row segment
        #pragma unroll
        for (int jr = 0; jr < 8; ++jr) {
            int row = jr * 8 + (tid >> 5);
            float Lv = lL[row];
            size_t roff = (size_t)(qbase + row) * SEQ + kbase + (tid & 31) * 4;
            uint2 w = *(const uint2*)(swsb + roff);
            union { unsigned u; float f; } t0, t1, t2, t3;
            t0.u = w.x << 16; t1.u = w.x & 0xFFFF0000u;
            t2.u = w.y << 16; t3.u = w.y & 0xFFFF0000u;
            f32x4 f;
            f.x = t0.f - Lv; f.y = t1.f - Lv; f.z = t2.f - Lv; f.w = t3.f - Lv;
            __builtin_nontemporal_store(f, (f32x4*)(attnG + (size_t)bh * SEQ * SEQ + roff));
        }
        __syncthreads();
    }

    // epilogue: out -= L * colsumv(quarter), store f32 partial
    int dcol = wv * 16 + l16;
    float csv = colsumv[((size_t)ksp * NB + b) * HDIM + h * DKV + dcol];
    float* dst = outh2 + (size_t)ksp * (8192 * HDIM);
    #pragma unroll
    for (int mt = 0; mt < 4; ++mt)
        #pragma unroll
        for (int r = 0; r < 4; ++r) {
            int q = qbase + mt * 16 + lq4 * 4 + r;
            float val = o[mt][r] - Lr[mt][r] * csv;
            dst[((size_t)b * SEQ + q) * HDIM + h * DKV + dcol] = val;
        }
}

// ---------------------------------------------------------------------------
// k_oproj: out = (sum of 4 outh2 quarters)[8192,128] @ Wo[128,512] + bo.
// grid (64, 4). Fuses the old k_comb.
__global__ __launch_bounds__(256) void k_oproj(
    const float* __restrict__ outh2, const unsigned short* __restrict__ Wot,
    const float* __restrict__ bo, float* __restrict__ outG) {
    __shared__ unsigned short lA2[128 * 128];  // swizzled
    __shared__ unsigned short lB2[128 * 128];  // swizzled
    const int row0 = blockIdx.x * 128, col0 = blockIdx.y * 128;
    const int tid = threadIdx.x, lane = tid & 63, wv = tid >> 6;
    const int l16 = lane & 15, lq4 = lane >> 4;
    const int wr = wv >> 1, wc = wv & 1;

    // A: sum 4 f32 quarters -> bf16 -> swizzled LDS
    #pragma unroll
    for (int jj = 0; jj < 8; ++jj) {
        int flat = jj * 256 + tid;
        int row = flat >> 4, c = flat & 15;
        size_t gr = (size_t)(row0 + row) * HDIM + c * 8;
        float s[8];
        #pragma unroll
        for (int i = 0; i < 8; ++i) s[i] = 0.f;
        #pragma unroll
        for (int qq = 0; qq < 4; ++qq) {
            const float4* p = (const float4*)(outh2 + (size_t)qq * 1048576 + gr);
            float4 x0 = p[0], x1 = p[1];
            s[0] += x0.x; s[1] += x0.y; s[2] += x0.z; s[3] += x0.w;
            s[4] += x1.x; s[5] += x1.y; s[6] += x1.z; s[7] += x1.w;
        }
        unsigned d0 = (unsigned)f2bf(s[0]) | ((unsigned)f2bf(s[1]) << 16);
        unsigned d1 = (unsigned)f2bf(s[2]) | ((unsigned)f2bf(s[3]) << 16);
        unsigned d2 = (unsigned)f2bf(s[4]) | ((unsigned)f2bf(s[5]) << 16);
        unsigned d3 = (unsigned)f2bf(s[6]) | ((unsigned)f2bf(s[7]) << 16);
        uint4 pk; pk.x = d0; pk.y = d1; pk.z = d2; pk.w = d3;
        *(uint4*)&lA2[row * 128 + ((c ^ (row & 15)) * 8)] = pk;
    }
    // B: async swizzled
    #pragma unroll
    for (int c = 0; c < 8; ++c) {
        int chunk = wv * 8 + c;
        int flat = chunk * 64 + lane;
        int row = flat >> 4, cp = flat & 15, cc = cp ^ (row & 15);
        const void* g = (const char*)Wot + ((size_t)(col0 + row) * 128 + cc * 8) * 2;
        void* l = (char*)lB2 + chunk * 1024 + lane * 16;
        async16(g, l);
    }
    __syncthreads();

    f32x4 acc[4][4];
    #pragma unroll
    for (int mt = 0; mt < 4; ++mt)
        #pragma unroll
        for (int nt = 0; nt < 4; ++nt) acc[mt][nt] = f32x4{0.f, 0.f, 0.f, 0.f};

    #pragma unroll
    for (int ks = 0; ks < 4; ++ks) {
        short8 a[4], bfr[4];
        #pragma unroll
        for (int mt = 0; mt < 4; ++mt) {
            int row = wr * 64 + mt * 16 + l16;
            a[mt] = *(const short8*)&lA2[row * 128 + (((ks * 4 + lq4) ^ (row & 15)) * 8)];
        }
        #pragma unroll
        for (int nt = 0; nt < 4; ++nt) {
            int row = wc * 64 + nt * 16 + l16;
            bfr[nt] = *(const short8*)&lB2[row * 128 + (((ks * 4 + lq4) ^ (row & 15)) * 8)];
        }
        #pragma unroll
        for (int mt = 0; mt < 4; ++mt)
            #pragma unroll
            for (int nt = 0; nt < 4; ++nt)
                acc[mt][nt] = __builtin_amdgcn_mfma_f32_16x16x32_bf16(
                    a[mt], bfr[nt], acc[mt][nt], 0, 0, 0);
    }

    #pragma unroll
    for (int nt = 0; nt < 4; ++nt) {
        int col = col0 + wc * 64 + nt * 16 + l16;
        float bb = bo[col];
        #pragma unroll
        for (int mt = 0; mt < 4; ++mt)
            #pragma unroll
            for (int r = 0; r < 4; ++r) {
                int row = row0 + wr * 64 + mt * 16 + lq4 * 4 + r;
                outG[(size_t)row * DM + col] = acc[mt][nt][r] + bb;
            }
    }
}

// ---------------------------------------------------------------------------
extern "C" void kernel_launch(void* const* d_in, const int* in_sizes, int n_in,
                              void* d_out, int out_size, void* d_ws, size_t ws_size,
                              hipStream_t stream) {
    (void)in_sizes; (void)n_in; (void)out_size; (void)ws_size;
    const float* Qg = (const float*)d_in[0];
    const float* Kg = (const float*)d_in[1];
    const float* Vg = (const float*)d_in[2];
    const int*   maskg = (const int*)d_in[3];
    const float* Wq = (const float*)d_in[4];
    const float* bq = (const float*)d_in[5];
    const float* Wk = (const float*)d_in[6];
    const float* bk = (const float*)d_in[7];
    const float* Wv = (const float*)d_in[8];
    const float* bv = (const float*)d_in[9];
    const float* Wo = (const float*)d_in[10];
    const float* bo = (const float*)d_in[11];

    char* ws = (char*)d_ws;
    unsigned short* qs    = (unsigned short*)(ws);                   // 4 MB
    unsigned short* kb    = (unsigned short*)(ws + (4  << 20));      // 4 MB
    unsigned short* vt    = (unsigned short*)(ws + (8  << 20));      // 4 MB
    unsigned short* sws   = (unsigned short*)(ws + (12 << 20));      // 64 MB
    float*          outh2 = (float*)(ws + (76 << 20));               // 16 MB
    float*          Lpart = (float*)(ws + (92 << 20));               // 256 KB
    float*          colsumv = (float*)(ws + (92 << 20) + 262144);    // 8 KB
    unsigned short* Wqt   = (unsigned short*)(ws + (92 << 20) + 524288);
    unsigned short* Wkt   = (unsigned short*)((char*)Wqt + 131072);
    unsigned short* Wvt   = (unsigned short*)((char*)Wkt + 131072);
    unsigned short* Wot   = (unsigned short*)((char*)Wvt + 131072);

    float* outG  = (float*)d_out;
    float* attnG = outG + (size_t)NB * SEQ * DM;

    (void)hipMemsetAsync(colsumv, 0, 16 * HDIM * sizeof(float), stream);
    hipLaunchKernelGGL(k_prep, dim3(1024), dim3(256), 0, stream,
                       Wq, Wk, Wv, Wo, Wqt, Wkt, Wvt, Wot);
    hipLaunchKernelGGL(k_proj, dim3(128, 3), dim3(256), 0, stream,
                       Qg, Kg, Vg, Wqt, Wkt, Wvt, bq, bk, bv, qs, kb, vt, colsumv);
    hipLaunchKernelGGL(k_pass1, dim3(1024), dim3(256), 0, stream,
                       qs, kb, maskg, sws, Lpart);
    hipLaunchKernelGGL(k_pass2, dim3(1024), dim3(256), 0, stream,
                       sws, vt, Lpart, colsumv, attnG, outh2);
    hipLaunchKernelGGL(k_oproj, dim3(64, 4), dim3(256), 0, stream,
                       outh2, Wot, bo, outG);
}

// Round 5
// 269.037 us; speedup vs baseline: 1.0741x; 1.0741x over previous
//
#include <hip/hip_runtime.h>

typedef __attribute__((ext_vector_type(8))) short short8;
typedef __attribute__((ext_vector_type(4))) float f32x4;

#define DEVI static __device__ __forceinline__

constexpr int NB   = 4;     // batch
constexpr int NH   = 2;     // heads
constexpr int SEQ  = 2048;  // Lq = Lk
constexpr int DM   = 512;   // d_model
constexpr int DKV  = 64;    // d_k = d_v
constexpr int HDIM = 128;   // NH * DKV
constexpr int ST   = 2050;  // sArr row stride (shorts): +2 pad -> bank = row mod 32, conflict-free frag reads

DEVI unsigned short f2bf(float f) {
    union { float f; unsigned u; } v; v.f = f;
    unsigned r = v.u + 0x7FFFu + ((v.u >> 16) & 1u);
    return (unsigned short)(r >> 16);
}
DEVI float bf2f(unsigned short s) {
    union { unsigned u; float f; } v; v.u = ((unsigned)s) << 16; return v.f;
}
// async global->LDS, 16B per lane. LDS dest = wave-uniform base + lane*16.
DEVI void async16(const void* g, void* l) {
    __builtin_amdgcn_global_load_lds(
        (const __attribute__((address_space(1))) unsigned int*)g,
        (__attribute__((address_space(3))) unsigned int*)l, 16, 0, 0);
}

// ---------------------------------------------------------------------------
// k_prep: weights f32 -> bf16, transposed so MFMA B-operand rows are K-contig.
__global__ __launch_bounds__(256) void k_prep(
    const float* __restrict__ Wq, const float* __restrict__ Wk,
    const float* __restrict__ Wv, const float* __restrict__ Wo,
    unsigned short* __restrict__ Wqt, unsigned short* __restrict__ Wkt,
    unsigned short* __restrict__ Wvt, unsigned short* __restrict__ Wot) {
    int id = blockIdx.x * 256 + threadIdx.x;        // 0 .. 262143
    int which = id >> 16;
    int rem = id & 65535;
    if (which < 3) {
        const float* W = which == 0 ? Wq : (which == 1 ? Wk : Wv);
        unsigned short* Wt = which == 0 ? Wqt : (which == 1 ? Wkt : Wvt);
        int n = rem >> 9, k = rem & 511;            // dst [128][512]
        Wt[rem] = f2bf(W[k * HDIM + n]);
    } else {
        int n = rem >> 7, k = rem & 127;            // dst [512][128]
        Wot[rem] = f2bf(Wo[k * DM + n]);
    }
}

// ---------------------------------------------------------------------------
// k_proj: X[8192,512] @ W[512,128] + b  ->  per-head bf16 layouts.
// Also accumulates colsumv[b][h*64+d] = sum_k v (FULL k range) for the
// out = S@V - L*colsumV decomposition used by k_attn.
__global__ __launch_bounds__(256) void k_proj(
    const float* __restrict__ Qg, const float* __restrict__ Kg, const float* __restrict__ Vg,
    const unsigned short* __restrict__ Wqt, const unsigned short* __restrict__ Wkt,
    const unsigned short* __restrict__ Wvt,
    const float* __restrict__ bq, const float* __restrict__ bk, const float* __restrict__ bv,
    unsigned short* __restrict__ qs, unsigned short* __restrict__ kb,
    unsigned short* __restrict__ vt, float* __restrict__ colsumv) {
    __shared__ unsigned short lA[64 * 72];    // A tile, +8 pad
    __shared__ unsigned short lB[128 * 64];   // B tile, xor-swizzled chunks

    const int y = blockIdx.y;
    const float* X = y == 0 ? Qg : (y == 1 ? Kg : Vg);
    const unsigned short* Wt = y == 0 ? Wqt : (y == 1 ? Wkt : Wvt);
    const float* bias = y == 0 ? bq : (y == 1 ? bk : bv);
    const float scal = y == 0 ? 0.125f : 1.0f;   // fold 1/sqrt(dk) into q
    const int row0 = blockIdx.x * 64;
    const int tid = threadIdx.x, lane = tid & 63, wv = tid >> 6;
    const int l16 = lane & 15, lq4 = lane >> 4;
    const int wr = wv >> 1, wc = wv & 1;

    f32x4 acc[2][4];
    #pragma unroll
    for (int i = 0; i < 2; ++i)
        #pragma unroll
        for (int j = 0; j < 4; ++j) acc[i][j] = f32x4{0.f, 0.f, 0.f, 0.f};

    const int arow = tid >> 2, ac0 = (tid & 3) * 16;

    for (int kc = 0; kc < 8; ++kc) {
        {
            const float* src = X + (size_t)(row0 + arow) * DM + kc * 64 + ac0;
            unsigned short* dst = &lA[arow * 72 + ac0];
            #pragma unroll
            for (int i = 0; i < 4; ++i) {
                f32x4 v = __builtin_nontemporal_load((const f32x4*)(src + 4 * i));
                unsigned p0 = (unsigned)f2bf(v.x) | ((unsigned)f2bf(v.y) << 16);
                unsigned p1 = (unsigned)f2bf(v.z) | ((unsigned)f2bf(v.w) << 16);
                *(unsigned*)(dst + 4 * i) = p0;
                *(unsigned*)(dst + 4 * i + 2) = p1;
            }
        }
        // stage B swizzled: chunk c' in LDS holds global chunk c = c'^(row&7)
        #pragma unroll
        for (int c = 0; c < 4; ++c) {
            int chunk = wv * 4 + c;
            int flat = chunk * 64 + lane;
            int row = flat >> 3, cp = flat & 7, cc = cp ^ (row & 7);
            const void* g = (const char*)Wt + (size_t)row * 1024 + kc * 128 + cc * 16;
            void* l = (char*)lB + chunk * 1024 + lane * 16;
            async16(g, l);
        }
        __syncthreads();

        #pragma unroll
        for (int ks = 0; ks < 2; ++ks) {
            short8 a[2], b[4];
            #pragma unroll
            for (int mt = 0; mt < 2; ++mt) {
                int m = wr * 32 + mt * 16 + l16;
                a[mt] = *(const short8*)&lA[m * 72 + ks * 32 + lq4 * 8];
            }
            #pragma unroll
            for (int nt = 0; nt < 4; ++nt) {
                int n = wc * 64 + nt * 16 + l16;
                b[nt] = *(const short8*)&lB[n * 64 + (((ks * 4 + lq4) ^ (n & 7)) * 8)];
            }
            #pragma unroll
            for (int mt = 0; mt < 2; ++mt)
                #pragma unroll
                for (int nt = 0; nt < 4; ++nt)
                    acc[mt][nt] = __builtin_amdgcn_mfma_f32_16x16x32_bf16(
                        a[mt], b[nt], acc[mt][nt], 0, 0, 0);
        }
        __syncthreads();
    }

    if (y < 2) {
        unsigned short* dstp = (y == 0) ? qs : kb;
        #pragma unroll
        for (int mt = 0; mt < 2; ++mt)
            #pragma unroll
            for (int nt = 0; nt < 4; ++nt) {
                int col = wc * 64 + nt * 16 + l16;
                float bb = bias[col];
                int h = col >> 6, d = col & 63;
                #pragma unroll
                for (int r = 0; r < 4; ++r) {
                    int row = row0 + wr * 32 + mt * 16 + lq4 * 4 + r;
                    int b = row >> 11, pos = row & 2047;
                    float val = (acc[mt][nt][r] + bb) * scal;
                    dstp[((size_t)(b * NH + h) * SEQ + pos) * DKV + d] = f2bf(val);
                }
            }
    } else {
        // V: bounce through LDS -> vt[b][h][d][kpos]; then colsum atomics.
        #pragma unroll
        for (int mt = 0; mt < 2; ++mt)
            #pragma unroll
            for (int nt = 0; nt < 4; ++nt) {
                int col = wc * 64 + nt * 16 + l16;
                float bb = bias[col];
                #pragma unroll
                for (int r = 0; r < 4; ++r) {
                    int mrow = wr * 32 + mt * 16 + lq4 * 4 + r;
                    lB[col * 64 + mrow] = f2bf(acc[mt][nt][r] + bb);
                }
            }
        __syncthreads();
        {
            int c = tid >> 1, mp = (tid & 1) * 32;
            int b = row0 >> 11, kpos0 = row0 & 2047;
            int h = c >> 6, d = c & 63;
            unsigned short* dst = vt + ((size_t)(b * NH + h) * DKV + d) * SEQ + kpos0 + mp;
            const unsigned short* srcl = &lB[c * 64 + mp];
            #pragma unroll
            for (int i = 0; i < 4; ++i)
                *(uint4*)(dst + 8 * i) = *(const uint4*)(srcl + 8 * i);
        }
        // colsum over this block's 64 k-positions (full-range accumulator)
        {
            int col = tid >> 1, half = tid & 1;
            const unsigned short* p = &lB[col * 64 + half * 32];
            float s = 0.f;
            #pragma unroll
            for (int i = 0; i < 4; ++i) {
                short8 hv = *(const short8*)(p + 8 * i);
                #pragma unroll
                for (int j = 0; j < 8; ++j) s += bf2f((unsigned short)hv[j]);
            }
            s += __shfl_xor(s, 1);
            if (half == 0) {
                int bb = row0 >> 11;
                atomicAdd(&colsumv[(size_t)bb * HDIM + col], s);
            }
        }
    }
}

// ---------------------------------------------------------------------------
// k_attn: fused. One block per (bh, 16-q-row tile). grid 1024 = 8 bh * 128 qt.
// Phase 1: loop 32 k-tiles (64 kpos): stage K wave-private (no barriers!),
//   QK^T MFMA, s = masked 10*tanh -> sArr (LDS), accumulate sum exp(s).
// Barrier; L = log(sum). Phase 2: loop k-tiles: stage V^T wave-private,
//   o += S@V. Then attn = s - L -> global (nontemporal), out = o - L*colsumv.
__global__ __launch_bounds__(256, 2) void k_attn(
    const unsigned short* __restrict__ qs, const unsigned short* __restrict__ kb,
    const unsigned short* __restrict__ vt, const int* __restrict__ maskg,
    const float* __restrict__ colsumv, float* __restrict__ attnG,
    unsigned short* __restrict__ outh) {
    __shared__ unsigned short sArr[16 * ST];     // 65,600 B  s tile [q][k]
    __shared__ unsigned short stage[64 * 64];    // 8,192 B   K / V^T staging
    __shared__ float lsumW[4 * 16];
    __shared__ float lL[16];

    const int bx = blockIdx.x;
    const int bh = bx & 7;            // XCD-swizzle: each XCD's L2 sees one bh
    const int qt = bx >> 3;
    const int qbase = qt * 16;
    const int b = bh >> 1, h = bh & 1;
    const int tid = threadIdx.x, lane = tid & 63, wv = tid >> 6;
    const int l16 = lane & 15, lq4 = lane >> 4;
    const int kcol = wv * 16 + l16;   // this lane's kpos offset within a 64-tile

    // Q fragments (16 rows x 64 d)
    short8 aq[2];
    #pragma unroll
    for (int ks = 0; ks < 2; ++ks)
        aq[ks] = *(const short8*)(qs +
            ((size_t)bh * SEQ + qbase + l16) * DKV + ks * 32 + lq4 * 8);

    const char* kbb = (const char*)(kb + (size_t)bh * SEQ * DKV);
    const char* vtb = (const char*)(vt + (size_t)bh * DKV * SEQ);

    // wave-private staging: wave w stages+consumes rows [wv*16, wv*16+16)
    auto issueK = [&](int kt) {
        int kbase = kt * 64;
        #pragma unroll
        for (int c = 0; c < 2; ++c) {
            int chunk = wv * 2 + c;
            int flat = chunk * 64 + lane;
            int row = flat >> 3, cp = flat & 7, cc = cp ^ (row & 7);
            async16(kbb + (size_t)(kbase + row) * 128 + cc * 16,
                    (char*)stage + chunk * 1024 + lane * 16);
        }
    };
    auto issueV = [&](int kt) {
        int kbase = kt * 64;
        #pragma unroll
        for (int c = 0; c < 2; ++c) {
            int chunk = wv * 2 + c;
            int flat = chunk * 64 + lane;
            int row = flat >> 3, cp = flat & 7, cc = cp ^ (row & 7);
            async16(vtb + (size_t)row * (SEQ * 2) + kbase * 2 + cc * 16,
                    (char*)stage + chunk * 1024 + lane * 16);
        }
    };

    // ---- phase 1: scores ----
    issueK(0);
    int mv = maskg[b * SEQ + kcol];
    float sums[4] = {0.f, 0.f, 0.f, 0.f};

    for (int kt = 0; kt < 32; ++kt) {
        int kbase = kt * 64;
        asm volatile("s_waitcnt vmcnt(0)" ::: "memory");
        short8 bfr[2];
        #pragma unroll
        for (int ks = 0; ks < 2; ++ks)
            bfr[ks] = *(const short8*)&stage[kcol * 64 + (((ks * 4 + lq4) ^ (kcol & 7)) * 8)];
        asm volatile("s_waitcnt lgkmcnt(0)" ::: "memory");
        int mv_cur = mv;
        if (kt < 31) {
            issueK(kt + 1);
            mv = maskg[b * SEQ + (kt + 1) * 64 + kcol];
        }
        f32x4 acc = {0.f, 0.f, 0.f, 0.f};
        acc = __builtin_amdgcn_mfma_f32_16x16x32_bf16(aq[0], bfr[0], acc, 0, 0, 0);
        acc = __builtin_amdgcn_mfma_f32_16x16x32_bf16(aq[1], bfr[1], acc, 0, 0, 0);
        // s = masked 10*tanh(x); exp(s) = e^10 * exp(-20*r), r=1/(1+e^{2x})
        #pragma unroll
        for (int r = 0; r < 4; ++r) {
            float x = acc[r];
            float e2 = __expf(2.f * x);
            float rr = __builtin_amdgcn_rcpf(1.f + e2);
            rr = mv_cur ? 1.f : rr;
            float s10 = __builtin_fmaf(-20.f, rr, 10.f);
            union { float f; unsigned u; } cv; cv.f = s10;
            sArr[(lq4 * 4 + r) * ST + kbase + kcol] = (unsigned short)(cv.u >> 16);
            float t = __expf(-20.f * rr);
            sums[r] = __builtin_fmaf(22026.465795f, t, sums[r]);
        }
    }

    // ---- L reduction ----
    #pragma unroll
    for (int r = 0; r < 4; ++r) {
        float v = sums[r];
        v += __shfl_xor(v, 1); v += __shfl_xor(v, 2);
        v += __shfl_xor(v, 4); v += __shfl_xor(v, 8);
        if (l16 == 0) lsumW[wv * 16 + lq4 * 4 + r] = v;
    }
    __syncthreads();
    if (tid < 16)
        lL[tid] = __logf(lsumW[tid] + lsumW[16 + tid] + lsumW[32 + tid] + lsumW[48 + tid]);
    __syncthreads();

    // ---- phase 2: PV ----
    issueV(0);
    f32x4 o = {0.f, 0.f, 0.f, 0.f};
    for (int kt = 0; kt < 32; ++kt) {
        int kbase = kt * 64;
        asm volatile("s_waitcnt vmcnt(0)" ::: "memory");
        short8 bfr[2], af[2];
        #pragma unroll
        for (int ks = 0; ks < 2; ++ks) {
            bfr[ks] = *(const short8*)&stage[kcol * 64 + (((ks * 4 + lq4) ^ (kcol & 7)) * 8)];
            af[ks]  = *(const short8*)&sArr[l16 * ST + kbase + ks * 32 + lq4 * 8];
        }
        asm volatile("s_waitcnt lgkmcnt(0)" ::: "memory");
        if (kt < 31) issueV(kt + 1);
        o = __builtin_amdgcn_mfma_f32_16x16x32_bf16(af[0], bfr[0], o, 0, 0, 0);
        o = __builtin_amdgcn_mfma_f32_16x16x32_bf16(af[1], bfr[1], o, 0, 0, 0);
    }

    // ---- attn = s - L -> global, nontemporal, coalesced 256B segments ----
    {
        int wrow = tid >> 4, wj = tid & 15;
        float Lv = lL[wrow];
        const unsigned short* srow = &sArr[wrow * ST];
        float* grow = attnG + ((size_t)bh * SEQ + qbase + wrow) * SEQ;
        #pragma unroll 4
        for (int i = 0; i < 32; ++i) {
            int col = i * 64 + wj * 4;
            uint2 w = *(const uint2*)(srow + col);
            union { unsigned u; float f; } t0, t1, t2, t3;
            t0.u = w.x << 16; t1.u = w.x & 0xFFFF0000u;
            t2.u = w.y << 16; t3.u = w.y & 0xFFFF0000u;
            f32x4 f;
            f.x = t0.f - Lv; f.y = t1.f - Lv; f.z = t2.f - Lv; f.w = t3.f - Lv;
            __builtin_nontemporal_store(f, (f32x4*)(grow + col));
        }
    }

    // ---- out epilogue: o - L*colsumv -> outh (bf16) ----
    {
        int d = wv * 16 + l16;
        float csv = colsumv[(size_t)b * HDIM + h * DKV + d];
        #pragma unroll
        for (int r = 0; r < 4; ++r) {
            int q = qbase + lq4 * 4 + r;
            float val = o[r] - lL[lq4 * 4 + r] * csv;
            outh[((size_t)b * SEQ + q) * HDIM + h * DKV + d] = f2bf(val);
        }
    }
}

// ---------------------------------------------------------------------------
// k_oproj: out = outh[8192,128] @ Wo[128,512] + bo.  grid (64, 4).
__global__ __launch_bounds__(256) void k_oproj(
    const unsigned short* __restrict__ outh, const unsigned short* __restrict__ Wot,
    const float* __restrict__ bo, float* __restrict__ outG) {
    __shared__ unsigned short lA2[128 * 128];  // swizzled
    __shared__ unsigned short lB2[128 * 128];  // swizzled
    const int row0 = blockIdx.x * 128, col0 = blockIdx.y * 128;
    const int tid = threadIdx.x, lane = tid & 63, wv = tid >> 6;
    const int l16 = lane & 15, lq4 = lane >> 4;
    const int wr = wv >> 1, wc = wv & 1;

    #pragma unroll
    for (int c = 0; c < 8; ++c) {
        int chunk = wv * 8 + c;
        int flat = chunk * 64 + lane;
        int row = flat >> 4, cp = flat & 15, cc = cp ^ (row & 15);
        const void* g = (const char*)outh + (size_t)(row0 + row) * 256 + cc * 16;
        async16(g, (char*)lA2 + chunk * 1024 + lane * 16);
    }
    #pragma unroll
    for (int c = 0; c < 8; ++c) {
        int chunk = wv * 8 + c;
        int flat = chunk * 64 + lane;
        int row = flat >> 4, cp = flat & 15, cc = cp ^ (row & 15);
        const void* g = (const char*)Wot + ((size_t)(col0 + row) * 128 + cc * 8) * 2;
        async16(g, (char*)lB2 + chunk * 1024 + lane * 16);
    }
    __syncthreads();

    f32x4 acc[4][4];
    #pragma unroll
    for (int mt = 0; mt < 4; ++mt)
        #pragma unroll
        for (int nt = 0; nt < 4; ++nt) acc[mt][nt] = f32x4{0.f, 0.f, 0.f, 0.f};

    #pragma unroll
    for (int ks = 0; ks < 4; ++ks) {
        short8 a[4], bfr[4];
        #pragma unroll
        for (int mt = 0; mt < 4; ++mt) {
            int row = wr * 64 + mt * 16 + l16;
            a[mt] = *(const short8*)&lA2[row * 128 + (((ks * 4 + lq4) ^ (row & 15)) * 8)];
        }
        #pragma unroll
        for (int nt = 0; nt < 4; ++nt) {
            int row = wc * 64 + nt * 16 + l16;
            bfr[nt] = *(const short8*)&lB2[row * 128 + (((ks * 4 + lq4) ^ (row & 15)) * 8)];
        }
        #pragma unroll
        for (int mt = 0; mt < 4; ++mt)
            #pragma unroll
            for (int nt = 0; nt < 4; ++nt)
                acc[mt][nt] = __builtin_amdgcn_mfma_f32_16x16x32_bf16(
                    a[mt], bfr[nt], acc[mt][nt], 0, 0, 0);
    }

    #pragma unroll
    for (int nt = 0; nt < 4; ++nt) {
        int col = col0 + wc * 64 + nt * 16 + l16;
        float bb = bo[col];
        #pragma unroll
        for (int mt = 0; mt < 4; ++mt)
            #pragma unroll
            for (int r = 0; r < 4; ++r) {
                int row = row0 + wr * 64 + mt * 16 + lq4 * 4 + r;
                outG[(size_t)row * DM + col] = acc[mt][nt][r] + bb;
            }
    }
}

// ---------------------------------------------------------------------------
extern "C" void kernel_launch(void* const* d_in, const int* in_sizes, int n_in,
                              void* d_out, int out_size, void* d_ws, size_t ws_size,
                              hipStream_t stream) {
    (void)in_sizes; (void)n_in; (void)out_size; (void)ws_size;
    const float* Qg = (const float*)d_in[0];
    const float* Kg = (const float*)d_in[1];
    const float* Vg = (const float*)d_in[2];
    const int*   maskg = (const int*)d_in[3];
    const float* Wq = (const float*)d_in[4];
    const float* bq = (const float*)d_in[5];
    const float* Wk = (const float*)d_in[6];
    const float* bk = (const float*)d_in[7];
    const float* Wv = (const float*)d_in[8];
    const float* bv = (const float*)d_in[9];
    const float* Wo = (const float*)d_in[10];
    const float* bo = (const float*)d_in[11];

    char* ws = (char*)d_ws;
    unsigned short* qs      = (unsigned short*)(ws);               // 4 MB
    unsigned short* kb      = (unsigned short*)(ws + (4  << 20));  // 4 MB
    unsigned short* vt      = (unsigned short*)(ws + (8  << 20));  // 4 MB
    unsigned short* outh    = (unsigned short*)(ws + (12 << 20));  // 2 MB
    float*          colsumv = (float*)(ws + (14 << 20));           // 2 KB
    unsigned short* Wqt     = (unsigned short*)(ws + (14 << 20) + 8192);
    unsigned short* Wkt     = (unsigned short*)((char*)Wqt + 131072);
    unsigned short* Wvt     = (unsigned short*)((char*)Wkt + 131072);
    unsigned short* Wot     = (unsigned short*)((char*)Wvt + 131072);

    float* outG  = (float*)d_out;
    float* attnG = outG + (size_t)NB * SEQ * DM;

    (void)hipMemsetAsync(colsumv, 0, NB * HDIM * sizeof(float), stream);
    hipLaunchKernelGGL(k_prep, dim3(1024), dim3(256), 0, stream,
                       Wq, Wk, Wv, Wo, Wqt, Wkt, Wvt, Wot);
    hipLaunchKernelGGL(k_proj, dim3(128, 3), dim3(256), 0, stream,
                       Qg, Kg, Vg, Wqt, Wkt, Wvt, bq, bk, bv, qs, kb, vt, colsumv);
    hipLaunchKernelGGL(k_attn, dim3(1024), dim3(256), 0, stream,
                       qs, kb, vt, maskg, colsumv, attnG, outh);
    hipLaunchKernelGGL(k_oproj, dim3(64, 4), dim3(256), 0, stream,
                       outh, Wot, bo, outG);
}